// Round 4
// baseline (585.404 us; speedup 1.0000x reference)
//
#include <hip/hip_runtime.h>

#define BATCH   2048
#define DIM     512
#define DB_N    50000
#define TOPK    5
#define PADN    50176       // 196 tiles of 256
#define NCHUNK  32
#define TM      256
#define TN      256
#define NFIN    12          // refined finalist pool

typedef float f32x4 __attribute__((ext_vector_type(4)));
typedef long long i64;

__device__ __forceinline__ void async16(const void* g, void* l) {
    __builtin_amdgcn_global_load_lds(
        (const __attribute__((address_space(1))) unsigned int*)g,
        (__attribute__((address_space(3))) unsigned int*)l, 16, 0, 0);
}

__device__ __forceinline__ short f2bf(float f) {
    union { float f; unsigned u; } v; v.f = f;
    unsigned r = v.u + 0x7FFFu + ((v.u >> 16) & 1u);
    return (short)(r >> 16);
}

// ============ convert: L2-normalize rows, scale x16, quantize to fp8 e4m3, ============
// ============ k-chunk + 16B-preserving pair-swizzle; optionally store inv norm ========
// dst byte layout: ((kb*NROWS + r)*64) + ((w ^ (r&6))<<3)  holds row r, k in
// [kb*64 + w*8, +8). DMA of 64 linear bytes per row then lands so that
// ds_read addr  r*64 + (x ^ ((r&6)<<3)) returns k-offset x.
template<int NROWS>
__global__ void convert_kernel(const float* __restrict__ src, unsigned char* __restrict__ dst,
                               float* __restrict__ invp, int nreal) {
    const int r    = blockIdx.x * 4 + (threadIdx.x >> 6);
    const int lane = threadIdx.x & 63;
    float4 a = {0,0,0,0}, b = {0,0,0,0};
    float ss = 0.f;
    if (r < nreal) {
        const float* row = src + (size_t)r * DIM;
        a = *(const float4*)(row + lane * 8);
        b = *(const float4*)(row + lane * 8 + 4);
        ss = a.x*a.x + a.y*a.y + a.z*a.z + a.w*a.w
           + b.x*b.x + b.y*b.y + b.z*b.z + b.w*b.w;
    }
    #pragma unroll
    for (int off = 1; off < 64; off <<= 1) ss += __shfl_xor(ss, off);
    const float inv = 1.0f / fmaxf(sqrtf(ss), 1e-12f);   // true inverse norm
    const float s16 = inv * 16.0f;                       // quantization scale
    int lo = __builtin_amdgcn_cvt_pk_fp8_f32(a.x * s16, a.y * s16, 0, false);
    lo     = __builtin_amdgcn_cvt_pk_fp8_f32(a.z * s16, a.w * s16, lo, true);
    int hi = __builtin_amdgcn_cvt_pk_fp8_f32(b.x * s16, b.y * s16, 0, false);
    hi     = __builtin_amdgcn_cvt_pk_fp8_f32(b.z * s16, b.w * s16, hi, true);
    const int kb = lane >> 3;
    const int w  = lane & 7;
    int2 u; u.x = lo; u.y = hi;
    *(int2*)(dst + ((size_t)kb * NROWS + r) * 64 + ((w ^ (r & 6)) << 3)) = u;
    if (invp && lane == 0) invp[r] = inv;
}

// ============ fused sim GEMM (fp8, 256x256, 8 waves, 8x4 frags) + running top-5 ============
__global__ __launch_bounds__(512, 2) void sim_topk_kernel(
    const unsigned char* __restrict__ hzf, const unsigned char* __restrict__ dbzf,
    unsigned* __restrict__ pc) {

    __shared__ __align__(16) unsigned char As[2][TM * 64];   // 2 x 16KB
    __shared__ __align__(16) unsigned char Bs[2][TN * 64];   // 2 x 16KB

    const int tid  = threadIdx.x;
    const int lane = tid & 63;
    const int l15  = lane & 15;
    const int lhi  = lane >> 4;
    const int wid  = tid >> 6;
    const int wm   = wid >> 2;            // 0..1
    const int wn   = wid & 3;             // 0..3
    const int rb   = blockIdx.x >> 5;     // 0..7
    const int mc   = blockIdx.x & 31;     // 0..31
    const int ts   = mc * 6 + (mc < 4 ? mc : 4);
    const int te   = ts + 6 + (mc < 4 ? 1 : 0);

    float tv0[TOPK], tv1[TOPK]; int ti0[TOPK], ti1[TOPK];
    #pragma unroll
    for (int j = 0; j < TOPK; ++j) {
        tv0[j] = -3.0e38f; tv1[j] = -3.0e38f; ti0[j] = 0; ti1[j] = 0;
    }

    auto STAGE = [&](int buf, int t, int kb) {
        const unsigned char* ab = hzf + ((size_t)kb * BATCH + rb * TM) * 64;
        const unsigned char* bb = dbzf + ((size_t)kb * PADN + t * TN) * 64;
        #pragma unroll
        for (int j = 0; j < 2; ++j) {
            const int u = tid + j * 512;
            async16(ab + (size_t)u * 16, &As[buf][u * 16]);
            async16(bb + (size_t)u * 16, &Bs[buf][u * 16]);
        }
    };

    f32x4 acc[8][4];

    STAGE(0, ts, 0);
    __syncthreads();

    int s = 0;
    for (int t = ts; t < te; ++t) {
        #pragma unroll
        for (int mf = 0; mf < 8; ++mf)
            #pragma unroll
            for (int nf = 0; nf < 4; ++nf) acc[mf][nf] = (f32x4){0.f, 0.f, 0.f, 0.f};

        #pragma unroll
        for (int kb = 0; kb < 8; ++kb) {
            const int nkb = (kb + 1) & 7;
            const int nt  = (kb == 7) ? t + 1 : t;
            if (nt < te) STAGE((s + 1) & 1, nt, nkb);

            const unsigned char* ta = As[s & 1];
            const unsigned char* tb = Bs[s & 1];
            #pragma unroll
            for (int ks = 0; ks < 2; ++ks) {
                const int swz = (ks * 32 + (lhi << 3)) ^ ((l15 & 6) << 3);
                i64 af[8], bf[4];
                #pragma unroll
                for (int mf = 0; mf < 8; ++mf)
                    af[mf] = *(const i64*)(ta + (wm * 128 + mf * 16 + l15) * 64 + swz);
                #pragma unroll
                for (int nf = 0; nf < 4; ++nf)
                    bf[nf] = *(const i64*)(tb + (wn * 64 + nf * 16 + l15) * 64 + swz);
                #pragma unroll
                for (int mf = 0; mf < 8; ++mf)
                    #pragma unroll
                    for (int nf = 0; nf < 4; ++nf)
                        acc[mf][nf] = __builtin_amdgcn_mfma_f32_16x16x32_fp8_fp8(
                            af[mf], bf[nf], acc[mf][nf], 0, 0, 0);
            }

            if (kb == 7) {
                // ---- per-tile top-5 epilogue (overlaps in-flight staging) ----
                const int n0 = t * TN;
                if (n0 + TN > DB_N) {
                    #pragma unroll
                    for (int nf = 0; nf < 4; ++nf) {
                        const bool valid = (n0 + wn * 64 + nf * 16 + l15) < DB_N;
                        #pragma unroll
                        for (int mf = 0; mf < 8; ++mf)
                            #pragma unroll
                            for (int i = 0; i < 4; ++i)
                                acc[mf][nf][i] = valid ? acc[mf][nf][i] : -3.0e38f;
                    }
                }
                #pragma unroll
                for (int mf = 0; mf < 8; ++mf) {
                    #pragma unroll
                    for (int i = 0; i < 4; ++i) {
                        const int osrc = (lane & 48) + ((mf & 3) << 2) + i;
                        float thr = __shfl((mf < 4) ? tv0[TOPK - 1] : tv1[TOPK - 1], osrc, 64);
                        float m = fmaxf(fmaxf(acc[mf][0][i], acc[mf][1][i]),
                                        fmaxf(acc[mf][2][i], acc[mf][3][i]));
                        #pragma unroll
                        for (int sh = 1; sh < 16; sh <<= 1) m = fmaxf(m, __shfl_xor(m, sh));
                        if (__any(m > thr)) {
                            #pragma unroll 1
                            for (int it = 0; it < TOPK; ++it) {
                                float v = acc[mf][0][i]; int c = l15;
                                #pragma unroll
                                for (int nf = 1; nf < 4; ++nf) {
                                    const float v2 = acc[mf][nf][i];
                                    const int   c2 = nf * 16 + l15;
                                    if (v2 > v) { v = v2; c = c2; }
                                }
                                #pragma unroll
                                for (int sh = 1; sh < 16; sh <<= 1) {
                                    const float ov = __shfl_xor(v, sh);
                                    const int   oc = __shfl_xor(c, sh);
                                    if (ov > v || (ov == v && oc < c)) { v = ov; c = oc; }
                                }
                                if (!__any(v > thr)) break;
                                const int gi = n0 + wn * 64 + c;
                                const bool owner = (l15 == ((mf & 3) << 2) + i);
                                if (owner && v > thr) {
                                    if (mf < 4) {
                                        #pragma unroll
                                        for (int j = TOPK - 1; j >= 1; --j) {
                                            const bool gt  = v > tv0[j];
                                            const bool gtp = v > tv0[j - 1];
                                            tv0[j] = gt ? (gtp ? tv0[j - 1] : v)  : tv0[j];
                                            ti0[j] = gt ? (gtp ? ti0[j - 1] : gi) : ti0[j];
                                        }
                                        if (v > tv0[0]) { tv0[0] = v; ti0[0] = gi; }
                                    } else {
                                        #pragma unroll
                                        for (int j = TOPK - 1; j >= 1; --j) {
                                            const bool gt  = v > tv1[j];
                                            const bool gtp = v > tv1[j - 1];
                                            tv1[j] = gt ? (gtp ? tv1[j - 1] : v)  : tv1[j];
                                            ti1[j] = gt ? (gtp ? ti1[j - 1] : gi) : ti1[j];
                                        }
                                        if (v > tv1[0]) { tv1[0] = v; ti1[0] = gi; }
                                    }
                                }
                                #pragma unroll
                                for (int nf = 0; nf < 4; ++nf)
                                    if (nf * 16 + l15 == c) acc[mf][nf][i] = -3.0e38f;
                                thr = __shfl((mf < 4) ? tv0[TOPK - 1] : tv1[TOPK - 1], osrc, 64);
                            }
                        }
                    }
                }
            }
            __syncthreads();
            ++s;
        }
    }

    // packed candidates: u32 = bf16(val)<<16 | idx (idx < 65536)
    #pragma unroll
    for (int slot = 0; slot < 2; ++slot) {
        const int mf  = (slot << 2) | (l15 >> 2);
        const int i   = l15 & 3;
        const int row = rb * TM + wm * 128 + mf * 16 + lhi * 4 + i;
        const size_t base = ((size_t)row * NCHUNK + mc) * TOPK;
        #pragma unroll
        for (int j = 0; j < TOPK; ++j) {
            const float v = slot ? tv1[j] : tv0[j];
            const int  ix = slot ? ti1[j] : ti0[j];
            pc[base + j] = (((unsigned)(unsigned short)f2bf(v)) << 16) | (unsigned)ix;
        }
    }
}

// ============ finalize: merge 160 -> top-12 (fp8 score), EXACT fp32 refine, ============
// ============ exact top-5 + softmax + gather + blend ============
__global__ void finalize_kernel(const float* __restrict__ h, const float* __restrict__ db,
                                const float* __restrict__ alpha_p,
                                const unsigned* __restrict__ pc,
                                const float* __restrict__ inv_db,
                                float* __restrict__ out) {
    const int b    = blockIdx.x;
    const int tid  = threadIdx.x;
    const int lane = tid & 63;
    const int wv   = tid >> 6;     // 4 waves
    const int NC   = NCHUNK * TOPK;   // 160

    __shared__ int   fid[NFIN];
    __shared__ float fsim[NFIN];
    __shared__ float invh_s;
    __shared__ float mu_s[TOPK];
    __shared__ int   id_s[TOPK];

    if (wv == 0) {
        // merge top-NFIN of 160 packed candidates (by fp8-derived score)
        const unsigned* cp = pc + (size_t)b * NC;
        float v[3]; int ix[3];
        #pragma unroll
        for (int j = 0; j < 3; ++j) {
            const int c  = lane + j * 64;
            const bool ok = c < NC;
            const unsigned u = ok ? cp[c] : 0u;
            v[j]  = ok ? __uint_as_float(u & 0xFFFF0000u) : -3.0e38f;
            ix[j] = ok ? (int)(u & 0xFFFFu) : 0x7fffffff;
        }
        for (int it = 0; it < NFIN; ++it) {
            float m = v[0]; int mi = ix[0];
            if (v[1] > m || (v[1] == m && ix[1] < mi)) { m = v[1]; mi = ix[1]; }
            if (v[2] > m || (v[2] == m && ix[2] < mi)) { m = v[2]; mi = ix[2]; }
            #pragma unroll
            for (int sh = 1; sh < 64; sh <<= 1) {
                const float om = __shfl_xor(m, sh);
                const int   oi = __shfl_xor(mi, sh);
                if (om > m || (om == m && oi < mi)) { m = om; mi = oi; }
            }
            if (lane == 0) fid[it] = mi;
            #pragma unroll
            for (int j = 0; j < 3; ++j) if (ix[j] == mi) v[j] = -3.0e38f;
        }
    } else if (wv == 1) {
        // exact h-row inverse norm
        const float* hr = h + (size_t)b * DIM;
        const float4 a = *(const float4*)(hr + lane * 8);
        const float4 c = *(const float4*)(hr + lane * 8 + 4);
        float ss = a.x*a.x + a.y*a.y + a.z*a.z + a.w*a.w
                 + c.x*c.x + c.y*c.y + c.z*c.z + c.w*c.w;
        #pragma unroll
        for (int off = 1; off < 64; off <<= 1) ss += __shfl_xor(ss, off);
        if (lane == 0) invh_s = 1.0f / fmaxf(sqrtf(ss), 1e-12f);
    }
    __syncthreads();

    // exact fp32 refinement of the NFIN finalists (3 per wave)
    const float* hr = h + (size_t)b * DIM;
    for (int f = wv; f < NFIN; f += 4) {
        const int gi = fid[f];
        const float* dr = db + (size_t)gi * DIM;
        const float4 ha = *(const float4*)(hr + lane * 8);
        const float4 hb = *(const float4*)(hr + lane * 8 + 4);
        const float4 da = *(const float4*)(dr + lane * 8);
        const float4 dc = *(const float4*)(dr + lane * 8 + 4);
        float d = ha.x*da.x + ha.y*da.y + ha.z*da.z + ha.w*da.w
                + hb.x*dc.x + hb.y*dc.y + hb.z*dc.z + hb.w*dc.w;
        #pragma unroll
        for (int off = 1; off < 64; off <<= 1) d += __shfl_xor(d, off);
        if (lane == 0) fsim[f] = d * invh_s * inv_db[gi];
    }
    __syncthreads();

    if (tid == 0) {
        // exact top-5 of NFIN (desc, tie -> smaller index)
        bool used[NFIN];
        #pragma unroll
        for (int j = 0; j < NFIN; ++j) used[j] = false;
        float bv[TOPK]; int bi[TOPK];
        for (int it = 0; it < TOPK; ++it) {
            float m = -3.0e38f; int mj = 0, mi = 0x7fffffff;
            for (int j = 0; j < NFIN; ++j) {
                if (used[j]) continue;
                if (fsim[j] > m || (fsim[j] == m && fid[j] < mi)) {
                    m = fsim[j]; mj = j; mi = fid[j];
                }
            }
            used[mj] = true; bv[it] = m; bi[it] = mi;
        }
        float ssum = 0.f, w[TOPK];
        #pragma unroll
        for (int j = 0; j < TOPK; ++j) { w[j] = expf(bv[j] - bv[0]); ssum += w[j]; }
        #pragma unroll
        for (int j = 0; j < TOPK; ++j) { mu_s[j] = w[j] / ssum; id_s[j] = bi[j]; }
    }
    __syncthreads();

    const float a = 1.0f / (1.0f + expf(-alpha_p[0]));
    for (int d = tid; d < DIM; d += 256) {
        float r = 0.f;
        #pragma unroll
        for (int j = 0; j < TOPK; ++j) r += mu_s[j] * db[(size_t)id_s[j] * DIM + d];
        out[(size_t)b * DIM + d] = a * h[(size_t)b * DIM + d] + (1.f - a) * r;
    }
}

extern "C" void kernel_launch(void* const* d_in, const int* in_sizes, int n_in,
                              void* d_out, int out_size, void* d_ws, size_t ws_size,
                              hipStream_t stream) {
    const float* h     = (const float*)d_in[0];
    const float* db    = (const float*)d_in[1];
    const float* alpha = (const float*)d_in[2];
    float* out = (float*)d_out;

    const size_t dbzf_bytes = (size_t)PADN * DIM;        // 25,690,112
    const size_t hzf_bytes  = (size_t)BATCH * DIM;       //  1,048,576
    const size_t inv_bytes  = (size_t)PADN * 4;          //    200,704

    unsigned char* dbzf   = (unsigned char*)d_ws;
    unsigned char* hzf    = (unsigned char*)d_ws + dbzf_bytes;
    float*         invdb  = (float*)((char*)d_ws + dbzf_bytes + hzf_bytes);
    unsigned*      pc     = (unsigned*)((char*)d_ws + dbzf_bytes + hzf_bytes + inv_bytes);

    convert_kernel<PADN><<<PADN / 4, 256, 0, stream>>>(db, dbzf, invdb, DB_N);
    convert_kernel<BATCH><<<BATCH / 4, 256, 0, stream>>>(h, hzf, nullptr, BATCH);
    sim_topk_kernel<<<8 * NCHUNK, 512, 0, stream>>>(hzf, dbzf, pc);
    finalize_kernel<<<BATCH, 256, 0, stream>>>(h, db, alpha, pc, invdb, out);
}